// Round 13
// baseline (87.486 us; speedup 1.0000x reference)
//
#include <hip/hip_runtime.h>

typedef unsigned short u16;
typedef unsigned char u8;
typedef long long i64;
typedef __bf16 bf16x8 __attribute__((ext_vector_type(8)));
typedef float f32x4 __attribute__((ext_vector_type(4)));
typedef float f32x16 __attribute__((ext_vector_type(16)));
typedef u16 u16x8 __attribute__((ext_vector_type(8)));

#define GLD16(g, l) __builtin_amdgcn_global_load_lds( \
    (const __attribute__((address_space(1))) void*)(g), \
    (__attribute__((address_space(3))) void*)(l), 16, 0, 0)
// counted vmcnt wait (N literal) -- lets prefetch loads stay in flight across barriers
#define VMW(N) asm volatile("s_waitcnt vmcnt(" #N ")" ::: "memory")
#define SCHB __builtin_amdgcn_sched_barrier(0)
#define SBAR __builtin_amdgcn_s_barrier()

__device__ __forceinline__ float bf2f(u16 u) {
  return __uint_as_float(((unsigned)u) << 16);
}
__device__ __forceinline__ u16 f2bf(float f) {  // RNE
  unsigned u = __float_as_uint(f);
  return (u16)((u + 0x7fffu + ((u >> 16) & 1u)) >> 16);
}
// ---- software fp8 e4m3fn fallback codec ----
__device__ __forceinline__ u8 f8e_sw(float v) {
  unsigned u = __float_as_uint(v);
  unsigned s = (u >> 24) & 0x80u;
  u &= 0x7fffffffu;
  if (u < 0x3c000000u) return (u8)s;
  int b = (int)((u + 0x7FFFFu + ((u >> 20) & 1u)) >> 20) - 960;
  b = b < 8 ? 8 : (b > 126 ? 126 : b);
  return (u8)(b | s);
}
// ---- hardware fp8 codec (gfx950) with sw fallback ----
__device__ __forceinline__ unsigned pk4(float a, float b, float c, float d) {
#if __has_builtin(__builtin_amdgcn_cvt_pk_fp8_f32)
  int r = __builtin_amdgcn_cvt_pk_fp8_f32(a, b, 0, false);
  r = __builtin_amdgcn_cvt_pk_fp8_f32(c, d, r, true);
  return (unsigned)r;
#else
  return (unsigned)f8e_sw(a) | ((unsigned)f8e_sw(b) << 8) |
         ((unsigned)f8e_sw(c) << 16) | ((unsigned)f8e_sw(d) << 24);
#endif
}
__device__ __forceinline__ u8 f8e1(float v) {
#if __has_builtin(__builtin_amdgcn_cvt_pk_fp8_f32)
  return (u8)(__builtin_amdgcn_cvt_pk_fp8_f32(v, v, 0, false) & 0xff);
#else
  return f8e_sw(v);
#endif
}
// 16B-slot swizzle key (bank-conflict-free fragment reads from GLD16-linear LDS)
__device__ __forceinline__ int sig(int r) { return (r ^ (r >> 3)) & 7; }

// ---- weight prep: wtT[d][c] = bf16(((Wq+Wk+Wv)/3)[c][d]);
//      wout8[d][c] = fp8(64 * w_out[c][d])  (x64 clears fp8 FTZ floor)
__global__ void combine_w(const float* __restrict__ wqkv, const float* __restrict__ wout,
                          u16* __restrict__ wtT, u8* __restrict__ wout8) {
  int c = blockIdx.x, d = threadIdx.x;
  float t = (wqkv[c * 768 + d] + wqkv[c * 768 + 256 + d] + wqkv[c * 768 + 512 + d]) * (1.0f / 3.0f);
  wtT[d * 256 + c] = f2bf(t);
  wout8[d * 256 + c] = f8e1(64.0f * wout[c * 256 + d]);
}

// ---- fused GroupNorm + GEMM-T, double-buffered. Tile 64x256, 8 waves.
__global__ __launch_bounds__(512) void gnT(
    const float* __restrict__ x, const float* __restrict__ gamma,
    const float* __restrict__ beta, const u16* __restrict__ wtT,
    u8* __restrict__ Q8, u8* __restrict__ Kt8) {
  __shared__ u16 lA[2][64 * 64];
  __shared__ u16 lB[2][256 * 64];
  const int m0 = blockIdx.x * 64;   // global pixel base (single batch per block)
  const int z = m0 >> 10;
  const int t = threadIdx.x, lane = t & 63;
  const int w = t >> 6, wr = w >> 2, wc = w & 3;
  f32x4 acc[2][4] = {};

#define GNT_STAGE(B, K0)                                                        \
  {                                                                             \
    _Pragma("unroll") for (int ch = 0; ch < 4; ch++) {                          \
      int flat = ch * 512 + t, row = flat >> 3, slot = flat & 7;                \
      GLD16(wtT + (size_t)row * 256 + (K0) + (slot ^ sig(row)) * 8,             \
            lB[B] + flat * 8);                                                  \
    }                                                                           \
    int row = t >> 3, grp = t & 7;                                              \
    const float* xp = x + (size_t)(m0 + row) * 256 + (K0) + grp * 8;            \
    float4 a = *(const float4*)xp, b = *(const float4*)(xp + 4);                \
    float mu = (a.x + a.y + a.z + a.w + b.x + b.y + b.z + b.w) * 0.125f;        \
    float d0 = a.x - mu, d1 = a.y - mu, d2 = a.z - mu, d3 = a.w - mu;           \
    float d4 = b.x - mu, d5 = b.y - mu, d6 = b.z - mu, d7 = b.w - mu;           \
    float var = (d0 * d0 + d1 * d1 + d2 * d2 + d3 * d3 +                        \
                 d4 * d4 + d5 * d5 + d6 * d6 + d7 * d7) * 0.125f;               \
    float rs = rsqrtf(var + 1e-6f);                                             \
    const float4 g0 = *(const float4*)(gamma + (K0) + grp * 8);                 \
    const float4 g1 = *(const float4*)(gamma + (K0) + grp * 8 + 4);             \
    const float4 e0 = *(const float4*)(beta + (K0) + grp * 8);                  \
    const float4 e1 = *(const float4*)(beta + (K0) + grp * 8 + 4);              \
    u16x8 o;                                                                    \
    o[0] = f2bf(g0.x * (d0 * rs) + e0.x); o[1] = f2bf(g0.y * (d1 * rs) + e0.y); \
    o[2] = f2bf(g0.z * (d2 * rs) + e0.z); o[3] = f2bf(g0.w * (d3 * rs) + e0.w); \
    o[4] = f2bf(g1.x * (d4 * rs) + e1.x); o[5] = f2bf(g1.y * (d5 * rs) + e1.y); \
    o[6] = f2bf(g1.z * (d6 * rs) + e1.z); o[7] = f2bf(g1.w * (d7 * rs) + e1.w); \
    *(u16x8*)(lA[B] + row * 64 + (grp ^ sig(row)) * 8) = o;                     \
  }

  GNT_STAGE(0, 0);
  __syncthreads();
  for (int it = 0; it < 4; it++) {
    if (it < 3) { GNT_STAGE((it + 1) & 1, (it + 1) * 64); }
    const u16* la = lA[it & 1];
    const u16* lb = lB[it & 1];
#pragma unroll
    for (int kk = 0; kk < 2; kk++) {
      bf16x8 af[2], bfr[4];
#pragma unroll
      for (int mi = 0; mi < 2; mi++) {
        int m = wr * 32 + mi * 16 + (lane & 15);
        af[mi] = *(const bf16x8*)(la + m * 64 + ((kk * 32 + (lane >> 4) * 8) ^ (sig(m) << 3)));
      }
#pragma unroll
      for (int ni = 0; ni < 4; ni++) {
        int n = wc * 64 + ni * 16 + (lane & 15);
        bfr[ni] = *(const bf16x8*)(lb + n * 64 + ((kk * 32 + (lane >> 4) * 8) ^ (sig(n) << 3)));
      }
#pragma unroll
      for (int mi = 0; mi < 2; mi++)
#pragma unroll
        for (int ni = 0; ni < 4; ni++)
          acc[mi][ni] = __builtin_amdgcn_mfma_f32_16x16x32_bf16(af[mi], bfr[ni], acc[mi][ni], 0, 0, 0);
    }
    __syncthreads();
  }

  const int rb = m0 + wr * 32 + ((lane >> 4) << 2);  // global pixel, %4 == 0
  const int cb = wc * 64 + (lane & 15);
  u8* kt = (u8*)lB[0];          // 16KB: Kt8 repack [1024 rows][16B]
  u8* qtile = (u8*)lB[1];       // 20KB: Q8 repack [256 c][80B stride, 64B data]
#pragma unroll
  for (int mi = 0; mi < 2; mi++)
#pragma unroll
    for (int ni = 0; ni < 4; ni++) {
      int P0 = rb + mi * 16, c = cb + ni * 16;
      int pl = P0 - m0;                     // 0..63, %4==0
      unsigned pk = pk4(acc[mi][ni][0], acc[mi][ni][1], acc[mi][ni][2], acc[mi][ni][3]);
#pragma unroll
      for (int j = 0; j < 4; j++)
        kt[(j * 256 + c) * 16 + (pl >> 2)] = (u8)(pk >> (8 * j));
      *(unsigned*)(qtile + c * 80 + pl) = pk;
    }
  __syncthreads();
  const int ckb = (m0 & 1023) >> 2;
  u8* Kz = Kt8 + (size_t)z * 262144;
  u8* Qz = Q8 + (size_t)z * 262144;
#pragma unroll
  for (int r2 = 0; r2 < 2; r2++) {
    int r = t * 2 + r2;
    uint4 v = *(const uint4*)(kt + r * 16);
    *(uint4*)(Kz + (size_t)r * 256 + ckb) = v;
  }
#pragma unroll
  for (int ph = 0; ph < 2; ph++) {
    int idx = ph * 512 + t, c = idx >> 2, q = idx & 3;
    uint4 v = *(const uint4*)(qtile + c * 80 + q * 16);
    *(uint4*)(Qz + (size_t)c * 1024 + (m0 & 1023) + q * 16) = v;
  }
#undef GNT_STAGE
}

// ---- GEMM-S (fp8): Et[p,i] = fp8(exp((Q@K)[i,p]/16)) + row partial sums.
// 2-stage BK=128 dbuf, counted vmcnt.
__global__ __launch_bounds__(256) void gemm_s8(
    const u8* __restrict__ Q8, const u8* __restrict__ Kt8,
    u8* __restrict__ Et, float* __restrict__ partials) {
  __shared__ u8 lA[2][128 * 128];
  __shared__ u8 lB[2][128 * 128];
  const int z = blockIdx.x;
  const int mb = blockIdx.y & 7, pb = blockIdx.y >> 3;
  const u8* Az = Q8 + (size_t)z * 262144;
  const u8* Bz = Kt8 + (size_t)z * 262144;
  u8* Ez = Et + (size_t)z * 1048576;
  const int m0 = mb * 128, n0 = pb * 128;
  const int t = threadIdx.x, lane = t & 63;
  const int wr = (t >> 6) >> 1, wc = (t >> 6) & 1;
  f32x4 acc[4][4] = {};

#define S8_STAGE(B, K0)                                                       \
  {                                                                           \
    _Pragma("unroll") for (int ch = 0; ch < 4; ch++) {                        \
      int flat = ch * 256 + t, row = flat >> 3, slot = flat & 7;              \
      GLD16(Az + (size_t)(m0 + row) * 256 + (K0) + (slot ^ sig(row)) * 16,    \
            lA[B] + flat * 16);                                               \
    }                                                                         \
    _Pragma("unroll") for (int ch = 0; ch < 4; ch++) {                        \
      int flat = ch * 256 + t, row = flat >> 3, slot = flat & 7;              \
      GLD16(Bz + (size_t)(n0 + row) * 256 + (K0) + (slot ^ sig(row)) * 16,    \
            lB[B] + flat * 16);                                               \
    }                                                                         \
  }
#define S8_COMP(LA, LB)                                                       \
  _Pragma("unroll") for (int kk = 0; kk < 4; kk++) {                          \
    i64 af[4], bfv[4];                                                        \
    int koff = kk * 32 + (lane >> 4) * 8;                                     \
    _Pragma("unroll") for (int mi = 0; mi < 4; mi++) {                        \
      int m = wr * 64 + mi * 16 + (lane & 15);                                \
      af[mi] = *(const i64*)((LA) + m * 128 + (koff ^ (sig(m) << 4)));        \
    }                                                                         \
    _Pragma("unroll") for (int ni = 0; ni < 4; ni++) {                        \
      int n = wc * 64 + ni * 16 + (lane & 15);                                \
      bfv[ni] = *(const i64*)((LB) + n * 128 + (koff ^ (sig(n) << 4)));       \
    }                                                                         \
    _Pragma("unroll") for (int mi = 0; mi < 4; mi++)                          \
      _Pragma("unroll") for (int ni = 0; ni < 4; ni++)                        \
        acc[mi][ni] = __builtin_amdgcn_mfma_f32_16x16x32_fp8_fp8(             \
            af[mi], bfv[ni], acc[mi][ni], 0, 0, 0);                           \
  }

  S8_STAGE(0, 0);
  S8_STAGE(1, 128);
  VMW(8); SCHB; SBAR; SCHB;
  __builtin_amdgcn_s_setprio(1);
  S8_COMP(lA[0], lB[0]);
  __builtin_amdgcn_s_setprio(0);
  VMW(0); SCHB; SBAR; SCHB;
  __builtin_amdgcn_s_setprio(1);
  S8_COMP(lA[1], lB[1]);
  __builtin_amdgcn_s_setprio(0);
  // NOTE: no barrier needed here -- epilogue writes go to lA[0], which no
  // wave reads after the VMW(0) barrier (second compute touches only idx-1).
#undef S8_STAGE
#undef S8_COMP

  u8* ldsC = lA[0];  // 128p x 128i fp8 tile (16KB)
  const int rbl = wr * 64 + ((lane >> 4) << 2);  // local i
  const int cbl = wc * 64 + (lane & 15);         // local p
  const float SCL = 0.0625f * 1.44269504089f;    // exp(x) = exp2(x*log2e)
  float ps[4][4] = {};
#pragma unroll
  for (int mi = 0; mi < 4; mi++)
#pragma unroll
    for (int ni = 0; ni < 4; ni++) {
      int pl = cbl + ni * 16, ib = rbl + mi * 16;
      float e0 = exp2f(acc[mi][ni][0] * SCL);
      float e1 = exp2f(acc[mi][ni][1] * SCL);
      float e2 = exp2f(acc[mi][ni][2] * SCL);
      float e3 = exp2f(acc[mi][ni][3] * SCL);
      ps[mi][0] += e0; ps[mi][1] += e1; ps[mi][2] += e2; ps[mi][3] += e3;
      *(unsigned*)(ldsC + pl * 128 + (ib ^ ((pl & 7) << 4))) = pk4(e0, e1, e2, e3);
    }
#pragma unroll
  for (int mi = 0; mi < 4; mi++)
#pragma unroll
    for (int j = 0; j < 4; j++) {
      float v = ps[mi][j];
      v += __shfl_xor(v, 1); v += __shfl_xor(v, 2);
      v += __shfl_xor(v, 4); v += __shfl_xor(v, 8);
      if ((lane & 15) == 0)
        partials[(size_t)(z * 1024 + m0 + rbl + mi * 16 + j) * 16 + pb * 2 + wc] = v;
    }
  __syncthreads();
#pragma unroll
  for (int ph = 0; ph < 4; ph++) {
    int pl = ph * 32 + (t >> 3), ich = (t & 7) * 16;
    uint4 v = *(const uint4*)(ldsC + pl * 128 + (ich ^ ((pl & 7) << 4)));
    *(uint4*)(Ez + (size_t)(n0 + pl) * 1024 + m0 + ich) = v;
  }
}

// ---- GEMM-G (fp8): Gt[d][i] = fp8( (128/L[i]) * sum_c wout8[d,c]*Q8[i,c] )
// (= fp8(8192 * rinv[i] * G[i,d]) since wout8 = 64*wout). Single-stage K=256,
// tile 256d x 128i, 8 waves (2x4). rinv reduction fused; LDS-repacked store.
__global__ __launch_bounds__(512) void gemm_g(
    const u8* __restrict__ wout8, const u8* __restrict__ Q8,
    const float* __restrict__ partials, u8* __restrict__ Gt) {
  __shared__ u8 lA[256 * 256];   // 64KB wout8 (whole A)
  __shared__ u8 lB[128 * 256];   // 32KB Q8 slice; reused as repack tile
  __shared__ float rv[128];
  const int z = blockIdx.x;      // grid (32, 8): id%8 == z%8 -> XCD locality
  const int i0 = blockIdx.y * 128;
  const u8* Bz = Q8 + (size_t)z * 262144;
  u8* Gz = Gt + (size_t)z * 262144;
  const int t = threadIdx.x, lane = t & 63;
  const int w = t >> 6, wr = w >> 2, wc = w & 3;  // wr: d-half, wc: i-quarter
#pragma unroll
  for (int ch = 0; ch < 8; ch++) {
    int flat = ch * 512 + t, row = flat >> 4, slot = flat & 15;
    GLD16(wout8 + (size_t)row * 256 + (slot ^ sig(row)) * 16, lA + flat * 16);
  }
#pragma unroll
  for (int ch = 0; ch < 4; ch++) {
    int flat = ch * 512 + t, row = flat >> 4, slot = flat & 15;
    GLD16(Bz + (size_t)(i0 + row) * 256 + (slot ^ sig(row)) * 16, lB + flat * 16);
  }
  if (t < 128) {  // rinv for this i-range (partials complete after gemm_s8)
    const float4* p = (const float4*)(partials + (size_t)(z * 1024 + i0 + t) * 16);
    float4 a = p[0], b = p[1], c = p[2], d = p[3];
    float s = ((a.x + a.y) + (a.z + a.w)) + ((b.x + b.y) + (b.z + b.w)) +
              ((c.x + c.y) + (c.z + c.w)) + ((d.x + d.y) + (d.z + d.w));
    rv[t] = 128.0f / s;
  }
  __syncthreads();
  f32x4 acc[8][2] = {};
#pragma unroll
  for (int kk = 0; kk < 8; kk++) {
    i64 af[8], bfv[2];
    int koff = kk * 32 + (lane >> 4) * 8;
#pragma unroll
    for (int mi = 0; mi < 8; mi++) {
      int m = wr * 128 + mi * 16 + (lane & 15);
      af[mi] = *(const i64*)(lA + m * 256 + (koff ^ (sig(m) << 4)));
    }
#pragma unroll
    for (int ni = 0; ni < 2; ni++) {
      int n = wc * 32 + ni * 16 + (lane & 15);
      bfv[ni] = *(const i64*)(lB + n * 256 + (koff ^ (sig(n) << 4)));
    }
#pragma unroll
    for (int mi = 0; mi < 8; mi++)
#pragma unroll
      for (int ni = 0; ni < 2; ni++)
        acc[mi][ni] = __builtin_amdgcn_mfma_f32_16x16x32_fp8_fp8(af[mi], bfv[ni], acc[mi][ni], 0, 0, 0);
  }
  __syncthreads();               // all lB fragment reads done
  u8* ldsG = lB;                 // repack [256 d][128 i], XOR-staggered
#pragma unroll
  for (int mi = 0; mi < 8; mi++)
#pragma unroll
    for (int ni = 0; ni < 2; ni++) {
      int i = wc * 32 + ni * 16 + (lane & 15);
      float r = rv[i];
#pragma unroll
      for (int j = 0; j < 4; j++) {
        int d = wr * 128 + mi * 16 + ((lane >> 4) << 2) + j;
        ldsG[d * 128 + (i ^ ((d & 7) << 4))] = f8e1(acc[mi][ni][j] * r);
      }
    }
  __syncthreads();
#pragma unroll
  for (int ch = 0; ch < 4; ch++) {
    int flat = ch * 512 + t, d = flat >> 3, q = flat & 7;
    uint4 v = *(const uint4*)(ldsG + d * 128 + ((q * 16) ^ ((d & 7) << 4)));
    *(uint4*)(Gz + (size_t)d * 1024 + i0 + q * 16) = v;
  }
}

// ---- GEMM-FIN (fp8, 32x32x16): final[p,d] = (1/8192)*sum_i Et[p,i]*Gt[d,i]
// + x[p,d]. 64p x 256d tile, 80KB LDS -> 2 blocks/CU, counted vmcnt(5).
// Per wave: 32m x 64n = 2 x mfma_32x32x16 per K=16 step (half the MFMA issues
// of the 16x16 version, +20% FLOP/cycle). C/D: col=lane&31,
// row=(reg&3)+8*(reg>>2)+4*(lane>>5) [m74/m101].
__global__ __launch_bounds__(512, 4) void gemm_fin(
    const u8* __restrict__ Et, const u8* __restrict__ Gt,
    const float* __restrict__ x, float* __restrict__ C) {
  __shared__ char smem[81920];
  const int z = blockIdx.x;      // grid (32, 16): id%8 == z%8 -> Gt panel per XCD
  const int m0 = blockIdx.y * 64;
  const u8* Az = Et + (size_t)z * 1048576;
  const u8* Bz = Gt + (size_t)z * 262144;
  const int t = threadIdx.x, lane = t & 63;
  const int w = t >> 6, wr = w >> 2, wc = w & 3;
  f32x16 acc[2] = {};

#define FIN_STAGE(B, K0)                                                      \
  {                                                                           \
    u8* la_ = (u8*)smem + (B) * 8192;                                         \
    u8* lb_ = (u8*)smem + 16384 + (B) * 32768;                                \
    {                                                                         \
      int row = t >> 3, slot = t & 7;                                         \
      GLD16(Az + (size_t)(m0 + row) * 1024 + (K0) + (slot ^ sig(row)) * 16,   \
            la_ + t * 16);                                                    \
    }                                                                         \
    _Pragma("unroll") for (int ch = 0; ch < 4; ch++) {                        \
      int flat = ch * 512 + t, row = flat >> 3, slot = flat & 7;              \
      GLD16(Bz + (size_t)row * 1024 + (K0) + (slot ^ sig(row)) * 16,          \
            lb_ + flat * 16);                                                 \
    }                                                                         \
  }

  FIN_STAGE(0, 0);
  for (int it = 0; it < 8; it++) {
    if (it < 7) {
      FIN_STAGE((it + 1) & 1, (it + 1) * 128);
      VMW(5);
    } else {
      VMW(0);
    }
    SCHB; SBAR; SCHB;
    const u8* la = (const u8*)smem + (it & 1) * 8192;
    const u8* lb = (const u8*)smem + 16384 + (it & 1) * 32768;
    __builtin_amdgcn_s_setprio(1);
#pragma unroll
    for (int ks = 0; ks < 8; ks++) {
      int koff = ks * 16 + (lane >> 5) * 8;
      int m = wr * 32 + (lane & 31);
      i64 af = *(const i64*)(la + m * 128 + (koff ^ (sig(m) << 4)));
      i64 bfv[2];
#pragma unroll
      for (int ni = 0; ni < 2; ni++) {
        int n = wc * 64 + ni * 32 + (lane & 31);
        bfv[ni] = *(const i64*)(lb + n * 128 + (koff ^ (sig(n) << 4)));
      }
#pragma unroll
      for (int ni = 0; ni < 2; ni++)
        acc[ni] = __builtin_amdgcn_mfma_f32_32x32x16_fp8_fp8(af, bfv[ni], acc[ni], 0, 0, 0);
    }
    __builtin_amdgcn_s_setprio(0);
    SBAR;
  }
#undef FIN_STAGE

  // epilogue: scale, spill f32 to [0,64K), coalesced x-add-store
  {
#pragma unroll
    for (int ni = 0; ni < 2; ni++)
#pragma unroll
      for (int r = 0; r < 16; r++) {
        int pl = wr * 32 + (r & 3) + 8 * (r >> 2) + 4 * (lane >> 5);
        int c = wc * 64 + ni * 32 + (lane & 31);
        *(float*)(smem + ((pl * 1024 + c * 4) ^ ((pl & 7) << 4))) =
            acc[ni][r] * (1.0f / 8192.0f);
      }
    __syncthreads();
    const size_t base = ((size_t)z * 1024 + m0) * 256;
#pragma unroll
    for (int pi = 0; pi < 8; pi++) {
      int f4 = pi * 512 + t;
      int row = f4 >> 6, ch = f4 & 63;
      f32x4 a = *(const f32x4*)(smem + row * 1024 + ((ch * 16) ^ ((row & 7) << 4)));
      const float4 xv = *(const float4*)(x + base + (size_t)f4 * 4);
      float4 o;
      o.x = a[0] + xv.x; o.y = a[1] + xv.y; o.z = a[2] + xv.z; o.w = a[3] + xv.w;
      *(float4*)(C + base + (size_t)f4 * 4) = o;
    }
  }
}

extern "C" void kernel_launch(void* const* d_in, const int* in_sizes, int n_in,
                              void* d_out, int out_size, void* d_ws, size_t ws_size,
                              hipStream_t stream) {
  (void)in_sizes; (void)n_in; (void)out_size; (void)ws_size;
  const float* x = (const float*)d_in[0];
  const float* gamma = (const float*)d_in[1];
  const float* beta = (const float*)d_in[2];
  const float* wqkv = (const float*)d_in[3];
  const float* wout = (const float*)d_in[4];
  float* outp = (float*)d_out;

  char* ws = (char*)d_ws;
  const size_t MB = 1024 * 1024;
  u16* wtT = (u16*)(ws + 0);                     // 128K bf16
  u8* wout8 = (u8*)(ws + (128 << 10));           // 64K  fp8 (64*w_out^T)
  float* partials = (float*)(ws + (512 << 10));  // 2M
  u8* Q8 = (u8*)(ws + 3 * MB);                   // 8M  fp8 Tt layout (Q rows flat)
  u8* Kt8 = (u8*)(ws + 12 * MB);                 // 8M  fp8 [z][1024][256]
  u8* Gt = (u8*)(ws + 21 * MB);                  // 8M  fp8 [z][256 d][1024 i]
  u8* Et = (u8*)(ws + 30 * MB);                  // 32M fp8 [z][p][i]

  combine_w<<<256, 256, 0, stream>>>(wqkv, wout, wtT, wout8);
  gnT<<<512, 512, 0, stream>>>(x, gamma, beta, wtT, Q8, Kt8);
  gemm_s8<<<dim3(32, 64), 256, 0, stream>>>(Q8, Kt8, Et, partials);
  gemm_g<<<dim3(32, 8), 512, 0, stream>>>(wout8, Q8, partials, Gt);
  gemm_fin<<<dim3(32, 16), 512, 0, stream>>>(Et, Gt, x, outp);
}

// Round 15
// 85.473 us; speedup vs baseline: 1.0236x; 1.0236x over previous
//
#include <hip/hip_runtime.h>

typedef unsigned short u16;
typedef unsigned char u8;
typedef long long i64;
typedef __bf16 bf16x8 __attribute__((ext_vector_type(8)));
typedef float f32x4 __attribute__((ext_vector_type(4)));
typedef u16 u16x8 __attribute__((ext_vector_type(8)));

#define GLD16(g, l) __builtin_amdgcn_global_load_lds( \
    (const __attribute__((address_space(1))) void*)(g), \
    (__attribute__((address_space(3))) void*)(l), 16, 0, 0)
// counted vmcnt wait (N literal) -- lets prefetch loads stay in flight across barriers
#define VMW(N) asm volatile("s_waitcnt vmcnt(" #N ")" ::: "memory")
#define SCHB __builtin_amdgcn_sched_barrier(0)
#define SBAR __builtin_amdgcn_s_barrier()

__device__ __forceinline__ float bf2f(u16 u) {
  return __uint_as_float(((unsigned)u) << 16);
}
__device__ __forceinline__ u16 f2bf(float f) {  // RNE
  unsigned u = __float_as_uint(f);
  return (u16)((u + 0x7fffu + ((u >> 16) & 1u)) >> 16);
}
// ---- software fp8 e4m3fn fallback codec ----
__device__ __forceinline__ u8 f8e_sw(float v) {
  unsigned u = __float_as_uint(v);
  unsigned s = (u >> 24) & 0x80u;
  u &= 0x7fffffffu;
  if (u < 0x3c000000u) return (u8)s;
  int b = (int)((u + 0x7FFFFu + ((u >> 20) & 1u)) >> 20) - 960;
  b = b < 8 ? 8 : (b > 126 ? 126 : b);
  return (u8)(b | s);
}
// ---- hardware fp8 codec (gfx950) with sw fallback ----
__device__ __forceinline__ unsigned pk4(float a, float b, float c, float d) {
#if __has_builtin(__builtin_amdgcn_cvt_pk_fp8_f32)
  int r = __builtin_amdgcn_cvt_pk_fp8_f32(a, b, 0, false);
  r = __builtin_amdgcn_cvt_pk_fp8_f32(c, d, r, true);
  return (unsigned)r;
#else
  return (unsigned)f8e_sw(a) | ((unsigned)f8e_sw(b) << 8) |
         ((unsigned)f8e_sw(c) << 16) | ((unsigned)f8e_sw(d) << 24);
#endif
}
__device__ __forceinline__ u8 f8e1(float v) {
#if __has_builtin(__builtin_amdgcn_cvt_pk_fp8_f32)
  return (u8)(__builtin_amdgcn_cvt_pk_fp8_f32(v, v, 0, false) & 0xff);
#else
  return f8e_sw(v);
#endif
}
// 16B-slot swizzle key (bank-conflict-free fragment reads from GLD16-linear LDS)
__device__ __forceinline__ int sig(int r) { return (r ^ (r >> 3)) & 7; }

// ---- weight prep: wtT[d][c] = bf16(((Wq+Wk+Wv)/3)[c][d]);
//      wout8[d][c] = fp8(64 * w_out[c][d])  (x64 clears fp8 FTZ floor)
__global__ void combine_w(const float* __restrict__ wqkv, const float* __restrict__ wout,
                          u16* __restrict__ wtT, u8* __restrict__ wout8) {
  int c = blockIdx.x, d = threadIdx.x;
  float t = (wqkv[c * 768 + d] + wqkv[c * 768 + 256 + d] + wqkv[c * 768 + 512 + d]) * (1.0f / 3.0f);
  wtT[d * 256 + c] = f2bf(t);
  wout8[d * 256 + c] = f8e1(64.0f * wout[c * 256 + d]);
}

// ---- fused GroupNorm + GEMM-T, double-buffered. Tile 64x256, 8 waves.
__global__ __launch_bounds__(512) void gnT(
    const float* __restrict__ x, const float* __restrict__ gamma,
    const float* __restrict__ beta, const u16* __restrict__ wtT,
    u8* __restrict__ Q8, u8* __restrict__ Kt8) {
  __shared__ u16 lA[2][64 * 64];
  __shared__ u16 lB[2][256 * 64];
  const int m0 = blockIdx.x * 64;   // global pixel base (single batch per block)
  const int z = m0 >> 10;
  const int t = threadIdx.x, lane = t & 63;
  const int w = t >> 6, wr = w >> 2, wc = w & 3;
  f32x4 acc[2][4] = {};

#define GNT_STAGE(B, K0)                                                        \
  {                                                                             \
    _Pragma("unroll") for (int ch = 0; ch < 4; ch++) {                          \
      int flat = ch * 512 + t, row = flat >> 3, slot = flat & 7;                \
      GLD16(wtT + (size_t)row * 256 + (K0) + (slot ^ sig(row)) * 8,             \
            lB[B] + flat * 8);                                                  \
    }                                                                           \
    int row = t >> 3, grp = t & 7;                                              \
    const float* xp = x + (size_t)(m0 + row) * 256 + (K0) + grp * 8;            \
    float4 a = *(const float4*)xp, b = *(const float4*)(xp + 4);                \
    float mu = (a.x + a.y + a.z + a.w + b.x + b.y + b.z + b.w) * 0.125f;        \
    float d0 = a.x - mu, d1 = a.y - mu, d2 = a.z - mu, d3 = a.w - mu;           \
    float d4 = b.x - mu, d5 = b.y - mu, d6 = b.z - mu, d7 = b.w - mu;           \
    float var = (d0 * d0 + d1 * d1 + d2 * d2 + d3 * d3 +                        \
                 d4 * d4 + d5 * d5 + d6 * d6 + d7 * d7) * 0.125f;               \
    float rs = rsqrtf(var + 1e-6f);                                             \
    const float4 g0 = *(const float4*)(gamma + (K0) + grp * 8);                 \
    const float4 g1 = *(const float4*)(gamma + (K0) + grp * 8 + 4);             \
    const float4 e0 = *(const float4*)(beta + (K0) + grp * 8);                  \
    const float4 e1 = *(const float4*)(beta + (K0) + grp * 8 + 4);              \
    u16x8 o;                                                                    \
    o[0] = f2bf(g0.x * (d0 * rs) + e0.x); o[1] = f2bf(g0.y * (d1 * rs) + e0.y); \
    o[2] = f2bf(g0.z * (d2 * rs) + e0.z); o[3] = f2bf(g0.w * (d3 * rs) + e0.w); \
    o[4] = f2bf(g1.x * (d4 * rs) + e1.x); o[5] = f2bf(g1.y * (d5 * rs) + e1.y); \
    o[6] = f2bf(g1.z * (d6 * rs) + e1.z); o[7] = f2bf(g1.w * (d7 * rs) + e1.w); \
    *(u16x8*)(lA[B] + row * 64 + (grp ^ sig(row)) * 8) = o;                     \
  }

  GNT_STAGE(0, 0);
  __syncthreads();
  for (int it = 0; it < 4; it++) {
    if (it < 3) { GNT_STAGE((it + 1) & 1, (it + 1) * 64); }
    const u16* la = lA[it & 1];
    const u16* lb = lB[it & 1];
#pragma unroll
    for (int kk = 0; kk < 2; kk++) {
      bf16x8 af[2], bfr[4];
#pragma unroll
      for (int mi = 0; mi < 2; mi++) {
        int m = wr * 32 + mi * 16 + (lane & 15);
        af[mi] = *(const bf16x8*)(la + m * 64 + ((kk * 32 + (lane >> 4) * 8) ^ (sig(m) << 3)));
      }
#pragma unroll
      for (int ni = 0; ni < 4; ni++) {
        int n = wc * 64 + ni * 16 + (lane & 15);
        bfr[ni] = *(const bf16x8*)(lb + n * 64 + ((kk * 32 + (lane >> 4) * 8) ^ (sig(n) << 3)));
      }
#pragma unroll
      for (int mi = 0; mi < 2; mi++)
#pragma unroll
        for (int ni = 0; ni < 4; ni++)
          acc[mi][ni] = __builtin_amdgcn_mfma_f32_16x16x32_bf16(af[mi], bfr[ni], acc[mi][ni], 0, 0, 0);
    }
    __syncthreads();
  }

  const int rb = m0 + wr * 32 + ((lane >> 4) << 2);  // global pixel, %4 == 0
  const int cb = wc * 64 + (lane & 15);
  u8* kt = (u8*)lB[0];          // 16KB: Kt8 repack [1024 rows][16B]
  u8* qtile = (u8*)lB[1];       // 20KB: Q8 repack [256 c][80B stride, 64B data]
#pragma unroll
  for (int mi = 0; mi < 2; mi++)
#pragma unroll
    for (int ni = 0; ni < 4; ni++) {
      int P0 = rb + mi * 16, c = cb + ni * 16;
      int pl = P0 - m0;                     // 0..63, %4==0
      unsigned pk = pk4(acc[mi][ni][0], acc[mi][ni][1], acc[mi][ni][2], acc[mi][ni][3]);
#pragma unroll
      for (int j = 0; j < 4; j++)
        kt[(j * 256 + c) * 16 + (pl >> 2)] = (u8)(pk >> (8 * j));
      *(unsigned*)(qtile + c * 80 + pl) = pk;
    }
  __syncthreads();
  const int ckb = (m0 & 1023) >> 2;
  u8* Kz = Kt8 + (size_t)z * 262144;
  u8* Qz = Q8 + (size_t)z * 262144;
#pragma unroll
  for (int r2 = 0; r2 < 2; r2++) {
    int r = t * 2 + r2;
    uint4 v = *(const uint4*)(kt + r * 16);
    *(uint4*)(Kz + (size_t)r * 256 + ckb) = v;
  }
#pragma unroll
  for (int ph = 0; ph < 2; ph++) {
    int idx = ph * 512 + t, c = idx >> 2, q = idx & 3;
    uint4 v = *(const uint4*)(qtile + c * 80 + q * 16);
    *(uint4*)(Qz + (size_t)c * 1024 + (m0 & 1023) + q * 16) = v;
  }
#undef GNT_STAGE
}

// ---- GEMM-S (fp8): Et[p,i] = fp8(exp((Q@K)[i,p]/16)) + row partial sums.
// 2-stage BK=128 dbuf, counted vmcnt.
__global__ __launch_bounds__(256) void gemm_s8(
    const u8* __restrict__ Q8, const u8* __restrict__ Kt8,
    u8* __restrict__ Et, float* __restrict__ partials) {
  __shared__ u8 lA[2][128 * 128];
  __shared__ u8 lB[2][128 * 128];
  const int z = blockIdx.x;
  const int mb = blockIdx.y & 7, pb = blockIdx.y >> 3;
  const u8* Az = Q8 + (size_t)z * 262144;
  const u8* Bz = Kt8 + (size_t)z * 262144;
  u8* Ez = Et + (size_t)z * 1048576;
  const int m0 = mb * 128, n0 = pb * 128;
  const int t = threadIdx.x, lane = t & 63;
  const int wr = (t >> 6) >> 1, wc = (t >> 6) & 1;
  f32x4 acc[4][4] = {};

#define S8_STAGE(B, K0)                                                       \
  {                                                                           \
    _Pragma("unroll") for (int ch = 0; ch < 4; ch++) {                        \
      int flat = ch * 256 + t, row = flat >> 3, slot = flat & 7;              \
      GLD16(Az + (size_t)(m0 + row) * 256 + (K0) + (slot ^ sig(row)) * 16,    \
            lA[B] + flat * 16);                                               \
    }                                                                         \
    _Pragma("unroll") for (int ch = 0; ch < 4; ch++) {                        \
      int flat = ch * 256 + t, row = flat >> 3, slot = flat & 7;              \
      GLD16(Bz + (size_t)(n0 + row) * 256 + (K0) + (slot ^ sig(row)) * 16,    \
            lB[B] + flat * 16);                                               \
    }                                                                         \
  }
#define S8_COMP(LA, LB)                                                       \
  _Pragma("unroll") for (int kk = 0; kk < 4; kk++) {                          \
    i64 af[4], bfv[4];                                                        \
    int koff = kk * 32 + (lane >> 4) * 8;                                     \
    _Pragma("unroll") for (int mi = 0; mi < 4; mi++) {                        \
      int m = wr * 64 + mi * 16 + (lane & 15);                                \
      af[mi] = *(const i64*)((LA) + m * 128 + (koff ^ (sig(m) << 4)));        \
    }                                                                         \
    _Pragma("unroll") for (int ni = 0; ni < 4; ni++) {                        \
      int n = wc * 64 + ni * 16 + (lane & 15);                                \
      bfv[ni] = *(const i64*)((LB) + n * 128 + (koff ^ (sig(n) << 4)));       \
    }                                                                         \
    _Pragma("unroll") for (int mi = 0; mi < 4; mi++)                          \
      _Pragma("unroll") for (int ni = 0; ni < 4; ni++)                        \
        acc[mi][ni] = __builtin_amdgcn_mfma_f32_16x16x32_fp8_fp8(             \
            af[mi], bfv[ni], acc[mi][ni], 0, 0, 0);                           \
  }

  S8_STAGE(0, 0);
  S8_STAGE(1, 128);
  VMW(8); SCHB; SBAR; SCHB;
  __builtin_amdgcn_s_setprio(1);
  S8_COMP(lA[0], lB[0]);
  __builtin_amdgcn_s_setprio(0);
  VMW(0); SCHB; SBAR; SCHB;
  __builtin_amdgcn_s_setprio(1);
  S8_COMP(lA[1], lB[1]);
  __builtin_amdgcn_s_setprio(0);
  // NOTE: no barrier needed here -- epilogue writes go to lA[0], which no
  // wave reads after the VMW(0) barrier (second compute touches only idx-1).
#undef S8_STAGE
#undef S8_COMP

  u8* ldsC = lA[0];  // 128p x 128i fp8 tile (16KB)
  const int rbl = wr * 64 + ((lane >> 4) << 2);  // local i
  const int cbl = wc * 64 + (lane & 15);         // local p
  const float SCL = 0.0625f * 1.44269504089f;    // exp(x) = exp2(x*log2e)
  float ps[4][4] = {};
#pragma unroll
  for (int mi = 0; mi < 4; mi++)
#pragma unroll
    for (int ni = 0; ni < 4; ni++) {
      int pl = cbl + ni * 16, ib = rbl + mi * 16;
      float e0 = exp2f(acc[mi][ni][0] * SCL);
      float e1 = exp2f(acc[mi][ni][1] * SCL);
      float e2 = exp2f(acc[mi][ni][2] * SCL);
      float e3 = exp2f(acc[mi][ni][3] * SCL);
      ps[mi][0] += e0; ps[mi][1] += e1; ps[mi][2] += e2; ps[mi][3] += e3;
      *(unsigned*)(ldsC + pl * 128 + (ib ^ ((pl & 7) << 4))) = pk4(e0, e1, e2, e3);
    }
#pragma unroll
  for (int mi = 0; mi < 4; mi++)
#pragma unroll
    for (int j = 0; j < 4; j++) {
      float v = ps[mi][j];
      v += __shfl_xor(v, 1); v += __shfl_xor(v, 2);
      v += __shfl_xor(v, 4); v += __shfl_xor(v, 8);
      if ((lane & 15) == 0)
        partials[(size_t)(z * 1024 + m0 + rbl + mi * 16 + j) * 16 + pb * 2 + wc] = v;
    }
  __syncthreads();
#pragma unroll
  for (int ph = 0; ph < 4; ph++) {
    int pl = ph * 32 + (t >> 3), ich = (t & 7) * 16;
    uint4 v = *(const uint4*)(ldsC + pl * 128 + (ich ^ ((pl & 7) << 4)));
    *(uint4*)(Ez + (size_t)(n0 + pl) * 1024 + m0 + ich) = v;
  }
}

// ---- GEMM-G (fp8): Gt[d][i] = fp8( (128/L[i]) * sum_c wout8[d,c]*Q8[i,c] )
// (= fp8(8192 * rinv[i] * G[i,d]) since wout8 = 64*wout). Single-stage K=256,
// tile 256d x 128i, 8 waves (2x4). rinv reduction fused; LDS-repacked store.
__global__ __launch_bounds__(512) void gemm_g(
    const u8* __restrict__ wout8, const u8* __restrict__ Q8,
    const float* __restrict__ partials, u8* __restrict__ Gt) {
  __shared__ u8 lA[256 * 256];   // 64KB wout8 (whole A)
  __shared__ u8 lB[128 * 256];   // 32KB Q8 slice; reused as repack tile
  __shared__ float rv[128];
  const int z = blockIdx.x;      // grid (32, 8): id%8 == z%8 -> XCD locality
  const int i0 = blockIdx.y * 128;
  const u8* Bz = Q8 + (size_t)z * 262144;
  u8* Gz = Gt + (size_t)z * 262144;
  const int t = threadIdx.x, lane = t & 63;
  const int w = t >> 6, wr = w >> 2, wc = w & 3;  // wr: d-half, wc: i-quarter
#pragma unroll
  for (int ch = 0; ch < 8; ch++) {
    int flat = ch * 512 + t, row = flat >> 4, slot = flat & 15;
    GLD16(wout8 + (size_t)row * 256 + (slot ^ sig(row)) * 16, lA + flat * 16);
  }
#pragma unroll
  for (int ch = 0; ch < 4; ch++) {
    int flat = ch * 512 + t, row = flat >> 4, slot = flat & 15;
    GLD16(Bz + (size_t)(i0 + row) * 256 + (slot ^ sig(row)) * 16, lB + flat * 16);
  }
  if (t < 128) {  // rinv for this i-range (partials complete after gemm_s8)
    const float4* p = (const float4*)(partials + (size_t)(z * 1024 + i0 + t) * 16);
    float4 a = p[0], b = p[1], c = p[2], d = p[3];
    float s = ((a.x + a.y) + (a.z + a.w)) + ((b.x + b.y) + (b.z + b.w)) +
              ((c.x + c.y) + (c.z + c.w)) + ((d.x + d.y) + (d.z + d.w));
    rv[t] = 128.0f / s;
  }
  __syncthreads();
  f32x4 acc[8][2] = {};
#pragma unroll
  for (int kk = 0; kk < 8; kk++) {
    i64 af[8], bfv[2];
    int koff = kk * 32 + (lane >> 4) * 8;
#pragma unroll
    for (int mi = 0; mi < 8; mi++) {
      int m = wr * 128 + mi * 16 + (lane & 15);
      af[mi] = *(const i64*)(lA + m * 256 + (koff ^ (sig(m) << 4)));
    }
#pragma unroll
    for (int ni = 0; ni < 2; ni++) {
      int n = wc * 32 + ni * 16 + (lane & 15);
      bfv[ni] = *(const i64*)(lB + n * 256 + (koff ^ (sig(n) << 4)));
    }
#pragma unroll
    for (int mi = 0; mi < 8; mi++)
#pragma unroll
      for (int ni = 0; ni < 2; ni++)
        acc[mi][ni] = __builtin_amdgcn_mfma_f32_16x16x32_fp8_fp8(af[mi], bfv[ni], acc[mi][ni], 0, 0, 0);
  }
  __syncthreads();               // all lB fragment reads done
  u8* ldsG = lB;                 // repack [256 d][128 i], XOR-staggered
#pragma unroll
  for (int mi = 0; mi < 8; mi++)
#pragma unroll
    for (int ni = 0; ni < 2; ni++) {
      int i = wc * 32 + ni * 16 + (lane & 15);
      float r = rv[i];
#pragma unroll
      for (int j = 0; j < 4; j++) {
        int d = wr * 128 + mi * 16 + ((lane >> 4) << 2) + j;
        ldsG[d * 128 + (i ^ ((d & 7) << 4))] = f8e1(acc[mi][ni][j] * r);
      }
    }
  __syncthreads();
#pragma unroll
  for (int ch = 0; ch < 4; ch++) {
    int flat = ch * 512 + t, d = flat >> 3, q = flat & 7;
    uint4 v = *(const uint4*)(ldsG + d * 128 + ((q * 16) ^ ((d & 7) << 4)));
    *(uint4*)(Gz + (size_t)d * 1024 + i0 + q * 16) = v;
  }
}

// ---- GEMM-FIN (fp8, 16x16x32): final[p,d] = (1/8192)*sum_i Et[p,i]*Gt[d,i]
// + x[p,d]. 64p x 256d tile, 80KB LDS -> 2 blocks/CU, counted vmcnt(6)
// (exactly the 6 loads of the current buffer; next 6 stay in flight).
// Epilogue: f32 spill -> coalesced x-add-store.
__global__ __launch_bounds__(512, 4) void gemm_fin(
    const u8* __restrict__ Et, const u8* __restrict__ Gt,
    const float* __restrict__ x, float* __restrict__ C) {
  __shared__ char smem[81920];
  const int z = blockIdx.x;      // grid (32, 16): id%8 == z%8 -> Gt panel per XCD
  const int m0 = blockIdx.y * 64;
  const u8* Az = Et + (size_t)z * 1048576;
  const u8* Bz = Gt + (size_t)z * 262144;
  const int t = threadIdx.x, lane = t & 63;
  const int w = t >> 6, wr = w >> 2, wc = w & 3;
  f32x4 acc[2][4] = {};

#define FIN_STAGE(B, K0)                                                      \
  {                                                                           \
    u8* la_ = (u8*)smem + (B) * 8192;                                         \
    u8* lb_ = (u8*)smem + 16384 + (B) * 32768;                                \
    {                                                                         \
      int row = t >> 3, slot = t & 7;                                         \
      GLD16(Az + (size_t)(m0 + row) * 1024 + (K0) + (slot ^ sig(row)) * 16,   \
            la_ + t * 16);                                                    \
    }                                                                         \
    _Pragma("unroll") for (int ch = 0; ch < 4; ch++) {                        \
      int flat = ch * 512 + t, row = flat >> 3, slot = flat & 7;              \
      GLD16(Bz + (size_t)row * 1024 + (K0) + (slot ^ sig(row)) * 16,          \
            lb_ + flat * 16);                                                 \
    }                                                                         \
  }

  FIN_STAGE(0, 0);
  for (int it = 0; it < 8; it++) {
    if (it < 7) {
      FIN_STAGE((it + 1) & 1, (it + 1) * 128);
      VMW(6);
    } else {
      VMW(0);
    }
    SCHB; SBAR; SCHB;
    const u8* la = (const u8*)smem + (it & 1) * 8192;
    const u8* lb = (const u8*)smem + 16384 + (it & 1) * 32768;
    __builtin_amdgcn_s_setprio(1);
#pragma unroll
    for (int kk = 0; kk < 4; kk++) {
      i64 af[2], bfv[4];
      int koff = kk * 32 + (lane >> 4) * 8;
#pragma unroll
      for (int mi = 0; mi < 2; mi++) {
        int m = wr * 32 + mi * 16 + (lane & 15);
        af[mi] = *(const i64*)(la + m * 128 + (koff ^ (sig(m) << 4)));
      }
#pragma unroll
      for (int ni = 0; ni < 4; ni++) {
        int n = wc * 64 + ni * 16 + (lane & 15);
        bfv[ni] = *(const i64*)(lb + n * 128 + (koff ^ (sig(n) << 4)));
      }
#pragma unroll
      for (int mi = 0; mi < 2; mi++)
#pragma unroll
        for (int ni = 0; ni < 4; ni++)
          acc[mi][ni] = __builtin_amdgcn_mfma_f32_16x16x32_fp8_fp8(af[mi], bfv[ni], acc[mi][ni], 0, 0, 0);
    }
    __builtin_amdgcn_s_setprio(0);
    SBAR;
  }
#undef FIN_STAGE

  // epilogue: scale, spill f32 to [0,64K), coalesced x-add-store
  {
#pragma unroll
    for (int mi = 0; mi < 2; mi++)
#pragma unroll
      for (int ni = 0; ni < 4; ni++)
#pragma unroll
        for (int j = 0; j < 4; j++) {
          int pl = wr * 32 + mi * 16 + ((lane >> 4) << 2) + j;
          int c = wc * 64 + ni * 16 + (lane & 15);
          *(float*)(smem + ((pl * 1024 + c * 4) ^ ((pl & 7) << 4))) =
              acc[mi][ni][j] * (1.0f / 8192.0f);
        }
    __syncthreads();
    const size_t base = ((size_t)z * 1024 + m0) * 256;
#pragma unroll
    for (int pi = 0; pi < 8; pi++) {
      int f4 = pi * 512 + t;
      int row = f4 >> 6, ch = f4 & 63;
      f32x4 a = *(const f32x4*)(smem + row * 1024 + ((ch * 16) ^ ((row & 7) << 4)));
      const float4 xv = *(const float4*)(x + base + (size_t)f4 * 4);
      float4 o;
      o.x = a[0] + xv.x; o.y = a[1] + xv.y; o.z = a[2] + xv.z; o.w = a[3] + xv.w;
      *(float4*)(C + base + (size_t)f4 * 4) = o;
    }
  }
}

extern "C" void kernel_launch(void* const* d_in, const int* in_sizes, int n_in,
                              void* d_out, int out_size, void* d_ws, size_t ws_size,
                              hipStream_t stream) {
  (void)in_sizes; (void)n_in; (void)out_size; (void)ws_size;
  const float* x = (const float*)d_in[0];
  const float* gamma = (const float*)d_in[1];
  const float* beta = (const float*)d_in[2];
  const float* wqkv = (const float*)d_in[3];
  const float* wout = (const float*)d_in[4];
  float* outp = (float*)d_out;

  char* ws = (char*)d_ws;
  const size_t MB = 1024 * 1024;
  u16* wtT = (u16*)(ws + 0);                     // 128K bf16
  u8* wout8 = (u8*)(ws + (128 << 10));           // 64K  fp8 (64*w_out^T)
  float* partials = (float*)(ws + (512 << 10));  // 2M
  u8* Q8 = (u8*)(ws + 3 * MB);                   // 8M  fp8 Tt layout (Q rows flat)
  u8* Kt8 = (u8*)(ws + 12 * MB);                 // 8M  fp8 [z][1024][256]
  u8* Gt = (u8*)(ws + 21 * MB);                  // 8M  fp8 [z][256 d][1024 i]
  u8* Et = (u8*)(ws + 30 * MB);                  // 32M fp8 [z][p][i]

  combine_w<<<256, 256, 0, stream>>>(wqkv, wout, wtT, wout8);
  gnT<<<512, 512, 0, stream>>>(x, gamma, beta, wtT, Q8, Kt8);
  gemm_s8<<<dim3(32, 64), 256, 0, stream>>>(Q8, Kt8, Et, partials);
  gemm_g<<<dim3(32, 8), 512, 0, stream>>>(wout8, Q8, partials, Gt);
  gemm_fin<<<dim3(32, 16), 512, 0, stream>>>(Et, Gt, x, outp);
}